// Round 1
// baseline (396.624 us; speedup 1.0000x reference)
//
#include <hip/hip_runtime.h>
#include <cstdint>
#include <cstddef>

// ---------------------------------------------------------------------------
// out = cos(x @ Wp^T + phi) @ Wc^T
//   x: [32768,1024] fp32, Wp/Wc: [1024,1024] fp32, phi flat [1024] fp32.
// R4: replace the m97-structure 128x128 GEMM (vmcnt(0)-drain per K-step,
// 8-way LDS bank conflicts) with the 256x256 4-phase counted-vmcnt schedule
// (T2 xor-swizzle + T3/T4 counted vmcnt + T5 setprio). 8 waves (2Mx4N),
// BK=64, LDS 128 KiB double-buffered, K-half subtiles so staging waits are
// vmcnt(8)/vmcnt(4) -- never a full drain in the steady-state loop.
// Cast dispatch unchanged from R3.
// ---------------------------------------------------------------------------

typedef __attribute__((ext_vector_type(8))) short short8;
typedef __attribute__((ext_vector_type(4))) float f32x4;

__device__ __forceinline__ unsigned short f2bf(float f) {
  unsigned u = __float_as_uint(f);
  u += 0x7FFFu + ((u >> 16) & 1u);   // RNE
  return (unsigned short)(u >> 16);
}

__device__ __forceinline__ void async_load16(const void* g, const void* l) {
  __builtin_amdgcn_global_load_lds(
      (const __attribute__((address_space(1))) void*)g,
      (__attribute__((address_space(3))) void*)l,
      16, 0, 0);
}

// ------------------- x + Wp + Wc fp32 -> bf16, ONE dispatch -----------------
__global__ __launch_bounds__(256) void cast_all(
    const float* __restrict__ x, const float* __restrict__ Wp,
    const float* __restrict__ Wc, unsigned short* __restrict__ xb,
    unsigned short* __restrict__ wpb, unsigned short* __restrict__ wcb) {
  long i = ((long)blockIdx.x * 256 + threadIdx.x) * 4;  // < 35651584
  const float* s;
  unsigned short* d;
  long j;
  if (i < 33554432)      { s = x;  d = xb;  j = i; }
  else if (i < 34603008) { s = Wp; d = wpb; j = i - 33554432; }
  else                   { s = Wc; d = wcb; j = i - 34603008; }
  const float4 v = *(const float4*)(s + j);
  ushort4 o;
  o.x = f2bf(v.x); o.y = f2bf(v.y); o.z = f2bf(v.z); o.w = f2bf(v.w);
  *(ushort4*)(d + j) = o;
}

constexpr int BM = 256, BN = 256, BK = 64;
constexpr int Kdim = 1024, Ndim = 1024;
constexpr int KT = Kdim / BK;   // 16

// C[m,n] = sum_k A[m,k]*B[n,k]  (B row-major [N,K]).
// EPI==1: store bf16 cos(acc + phi[n]); EPI==0: store fp32 acc.
// 512 threads = 8 waves, wave grid 2(M) x 4(N); per-wave C tile 128x64.
// LDS tiles: [buf][kh][256 rows][32 cols] bf16 (64 B rows, 4x16B chunks).
// T2 swizzle: LDS(row, chunk p) holds global chunk p ^ ((row>>1)&3); applied
// on the GLOBAL source of global_load_lds (dest stays linear, guideline 21)
// and inverted on the ds_read address.
template <int EPI>
__global__ __launch_bounds__(512, 2) void gemm256(
    const unsigned short* __restrict__ A,   // [M,1024] bf16
    const unsigned short* __restrict__ B,   // [1024,1024] bf16
    const float* __restrict__ phi,
    void* __restrict__ Cout) {
  __shared__ unsigned short As[2][2][256][32];   // 64 KB
  __shared__ unsigned short Bs[2][2][256][32];   // 64 KB

  const int tid    = threadIdx.x;
  const int lane   = tid & 63;
  const int wv     = tid >> 6;        // 0..7
  const int wr     = wv >> 2;         // 0..1  (M wave)
  const int wc     = wv & 3;          // 0..3  (N wave)
  const int lane15 = lane & 15;
  const int quad   = lane >> 4;
  const int swz8   = (quad ^ ((lane15 >> 1) & 3)) * 8;  // ds_read chunk swizzle

  // Bijective XCD swizzle: 512 wgs = 8 XCDs x 64; 4 n-siblings contiguous so
  // each XCD holds complete A m-panels in its L2.
  const int wg   = ((blockIdx.x & 7) << 6) | (blockIdx.x >> 3);
  const long row0 = (long)(wg >> 2) * BM;
  const int  col0 = (wg & 3) * BN;

  // staging: per wave 2 x 1KB issues per (matrix, kh); lane l covers
  // row = base + l/4, chunk l&3; global source chunk is pre-swizzled.
  const int rsub  = lane >> 2;                          // 0..15
  const int csrc8 = ((lane & 3) ^ ((lane >> 3) & 3)) * 8;
  const int rA    = wv * 32 + rsub;                     // issue j=0 row

  // Issue order matters for vmcnt counting: kh0 {A,A,B,B} then kh1 {A,A,B,B}.
#define STAGE(KTIDX, NB)                                                      \
  {                                                                           \
    const unsigned short* ga0 = A + (row0 + rA) * Kdim + (KTIDX) * BK + csrc8;\
    const unsigned short* ga1 = ga0 + (long)16 * Kdim;                        \
    const unsigned short* gb0 =                                               \
        B + (long)(col0 + rA) * Kdim + (KTIDX) * BK + csrc8;                  \
    const unsigned short* gb1 = gb0 + (long)16 * Kdim;                        \
    _Pragma("unroll")                                                         \
    for (int kh = 0; kh < 2; ++kh) {                                          \
      async_load16(ga0 + kh * 32, &As[NB][kh][wv * 32][0]);                   \
      async_load16(ga1 + kh * 32, &As[NB][kh][wv * 32 + 16][0]);              \
      async_load16(gb0 + kh * 32, &Bs[NB][kh][wv * 32][0]);                   \
      async_load16(gb1 + kh * 32, &Bs[NB][kh][wv * 32 + 16][0]);              \
    }                                                                         \
  }

  f32x4 acc[8][4];
#pragma unroll
  for (int i = 0; i < 8; ++i)
#pragma unroll
    for (int n = 0; n < 4; ++n) {
      f32x4 z = {0.f, 0.f, 0.f, 0.f};
      acc[i][n] = z;
    }

  // Prologue: stage tile 0; wait for its kh0 halves (first 4 loads).
  STAGE(0, 0);
  asm volatile("s_waitcnt vmcnt(4)" ::: "memory");
  __builtin_amdgcn_s_barrier();

#pragma unroll 2
  for (int kt = 0; kt < KT; ++kt) {
    const int cur = kt & 1;
    short8 af[4], bfr[4];

    // ---------------- P0: (mh=0, kh=0) ----------------
#pragma unroll
    for (int i = 0; i < 4; ++i)
      af[i] = *(const short8*)(&As[cur][0][wr * 128 + i * 16 + lane15][swz8]);
#pragma unroll
    for (int i = 0; i < 4; ++i)
      bfr[i] = *(const short8*)(&Bs[cur][0][wc * 64 + i * 16 + lane15][swz8]);
    if (kt + 1 < KT) STAGE(kt + 1, cur ^ 1);   // 8 loads for next tile
    __builtin_amdgcn_s_barrier();
    asm volatile("s_waitcnt lgkmcnt(0)" ::: "memory");
    __builtin_amdgcn_sched_barrier(0);
    __builtin_amdgcn_s_setprio(1);
#pragma unroll
    for (int i = 0; i < 4; ++i)
#pragma unroll
      for (int n = 0; n < 4; ++n)
        acc[i][n] = __builtin_amdgcn_mfma_f32_16x16x32_bf16(
            af[i], bfr[n], acc[i][n], 0, 0, 0);
    __builtin_amdgcn_s_setprio(0);
    __builtin_amdgcn_sched_barrier(0);
    __builtin_amdgcn_s_barrier();

    // ---------------- P1: (mh=1, kh=0) ----------------  (bfr reused)
#pragma unroll
    for (int i = 0; i < 4; ++i)
      af[i] =
          *(const short8*)(&As[cur][0][wr * 128 + (4 + i) * 16 + lane15][swz8]);
    __builtin_amdgcn_s_barrier();
    asm volatile("s_waitcnt lgkmcnt(0)" ::: "memory");
    __builtin_amdgcn_sched_barrier(0);
    __builtin_amdgcn_s_setprio(1);
#pragma unroll
    for (int i = 0; i < 4; ++i)
#pragma unroll
      for (int n = 0; n < 4; ++n)
        acc[4 + i][n] = __builtin_amdgcn_mfma_f32_16x16x32_bf16(
            af[i], bfr[n], acc[4 + i][n], 0, 0, 0);
    __builtin_amdgcn_s_setprio(0);
    __builtin_amdgcn_sched_barrier(0);
    // Need THIS tile's kh1 halves before P2. Outstanding: <=4 of L(kt)-kh1
    // plus the 8 just issued for kt+1 -> vmcnt(8). Last tile: drain.
    if (kt == KT - 1) {
      asm volatile("s_waitcnt vmcnt(0)" ::: "memory");
    } else {
      asm volatile("s_waitcnt vmcnt(8)" ::: "memory");
    }
    __builtin_amdgcn_s_barrier();

    // ---------------- P2: (mh=0, kh=1) ----------------
#pragma unroll
    for (int i = 0; i < 4; ++i)
      af[i] = *(const short8*)(&As[cur][1][wr * 128 + i * 16 + lane15][swz8]);
#pragma unroll
    for (int i = 0; i < 4; ++i)
      bfr[i] = *(const short8*)(&Bs[cur][1][wc * 64 + i * 16 + lane15][swz8]);
    __builtin_amdgcn_s_barrier();
    asm volatile("s_waitcnt lgkmcnt(0)" ::: "memory");
    __builtin_amdgcn_sched_barrier(0);
    __builtin_amdgcn_s_setprio(1);
#pragma unroll
    for (int i = 0; i < 4; ++i)
#pragma unroll
      for (int n = 0; n < 4; ++n)
        acc[i][n] = __builtin_amdgcn_mfma_f32_16x16x32_bf16(
            af[i], bfr[n], acc[i][n], 0, 0, 0);
    __builtin_amdgcn_s_setprio(0);
    __builtin_amdgcn_sched_barrier(0);
    __builtin_amdgcn_s_barrier();

    // ---------------- P3: (mh=1, kh=1) ----------------
#pragma unroll
    for (int i = 0; i < 4; ++i)
      af[i] =
          *(const short8*)(&As[cur][1][wr * 128 + (4 + i) * 16 + lane15][swz8]);
    __builtin_amdgcn_s_barrier();
    asm volatile("s_waitcnt lgkmcnt(0)" ::: "memory");
    __builtin_amdgcn_sched_barrier(0);
    __builtin_amdgcn_s_setprio(1);
#pragma unroll
    for (int i = 0; i < 4; ++i)
#pragma unroll
      for (int n = 0; n < 4; ++n)
        acc[4 + i][n] = __builtin_amdgcn_mfma_f32_16x16x32_bf16(
            af[i], bfr[n], acc[4 + i][n], 0, 0, 0);
    __builtin_amdgcn_s_setprio(0);
    __builtin_amdgcn_sched_barrier(0);
    // Next tile's kh0 must have landed; leave its kh1 (4 newest) in flight.
    if (kt < KT - 1) {
      asm volatile("s_waitcnt vmcnt(4)" ::: "memory");
    }
    __builtin_amdgcn_s_barrier();
  }
#undef STAGE

  // C/D layout (m89-verified): col = lane&15, row = quad*4 + reg.
  if (EPI == 1) {
    unsigned short* Q = (unsigned short*)Cout;
    float ph[4];
#pragma unroll
    for (int n = 0; n < 4; ++n)
      ph[n] = phi[col0 + wc * 64 + n * 16 + lane15];
#pragma unroll
    for (int mi = 0; mi < 8; ++mi) {
      const long rbase = row0 + wr * 128 + mi * 16 + quad * 4;
#pragma unroll
      for (int n = 0; n < 4; ++n) {
        const int c = col0 + wc * 64 + n * 16 + lane15;
#pragma unroll
        for (int r = 0; r < 4; ++r) {
          float v = __cosf(acc[mi][n][r] + ph[n]);
          Q[(rbase + r) * Ndim + c] = f2bf(v);
        }
      }
    }
  } else {
    float* C = (float*)Cout;
#pragma unroll
    for (int mi = 0; mi < 8; ++mi) {
      const long rbase = row0 + wr * 128 + mi * 16 + quad * 4;
#pragma unroll
      for (int n = 0; n < 4; ++n) {
        const int c = col0 + wc * 64 + n * 16 + lane15;
#pragma unroll
        for (int r = 0; r < 4; ++r)
          C[(rbase + r) * Ndim + c] = acc[mi][n][r];
      }
    }
  }
}

// ------------------------------- launch -------------------------------------
extern "C" void kernel_launch(void* const* d_in, const int* in_sizes, int n_in,
                              void* d_out, int out_size, void* d_ws, size_t ws_size,
                              hipStream_t stream) {
  const float* x   = (const float*)d_in[0];
  const float* Wp  = (const float*)d_in[1];
  const float* Wc  = (const float*)d_in[2];
  const float* phi = (const float*)d_in[3];
  float* out = (float*)d_out;

  // ws: Abf @0 (64 MB), Qbf @64 MB (64 MB), Wpbf @128 MB (2 MB), Wcbf (2 MB)
  char* ws = (char*)d_ws;
  unsigned short* Abf  = (unsigned short*)(ws);
  unsigned short* Qbf  = (unsigned short*)(ws + (size_t)67108864);
  unsigned short* Wpbf = (unsigned short*)(ws + (size_t)134217728);
  unsigned short* Wcbf = (unsigned short*)(ws + (size_t)136314880);

  cast_all<<<34816, 256, 0, stream>>>(x, Wp, Wc, Abf, Wpbf, Wcbf);
  gemm256<1><<<512, 512, 0, stream>>>(Abf, Wpbf, phi, (void*)Qbf);
  gemm256<0><<<512, 512, 0, stream>>>(Qbf, Wcbf, nullptr, (void*)out);

  (void)in_sizes; (void)n_in; (void)out_size; (void)ws_size;
}

// Round 2
// 383.838 us; speedup vs baseline: 1.0333x; 1.0333x over previous
//
#include <hip/hip_runtime.h>
#include <cstdint>
#include <cstddef>

// ---------------------------------------------------------------------------
// out = cos(x @ Wp^T + phi) @ Wc^T
//   x: [32768,1024] fp32, Wp/Wc: [1024,1024] fp32, phi flat [1024] fp32.
// R5: deepen the R4 pipeline. R4 burst-staged 8 loads at P0 and its critical
// vmcnt(4) gated on loads only 3 phases old -> 28% MfmaUtil. Now staging is
// spread 2 loads/phase with 1.5-tile prefetch depth (kh0 region of the
// current buffer is dead after P1, so P2/P3 stage tile t+2's kh0 into it).
// Steady-state waits are vmcnt(8), every consumed load is 4-5 phases old,
// drain-to-0 only on the last tile. Cast kernel: grid-stride, 4096 blocks,
// 32B/lane/iter (was 34816 single-shot blocks - launch/latency suspect).
// ---------------------------------------------------------------------------

typedef __attribute__((ext_vector_type(8))) short short8;
typedef __attribute__((ext_vector_type(4))) float f32x4;

__device__ __forceinline__ unsigned short f2bf(float f) {
  unsigned u = __float_as_uint(f);
  u += 0x7FFFu + ((u >> 16) & 1u);   // RNE
  return (unsigned short)(u >> 16);
}

__device__ __forceinline__ void async_load16(const void* g, const void* l) {
  __builtin_amdgcn_global_load_lds(
      (const __attribute__((address_space(1))) void*)g,
      (__attribute__((address_space(3))) void*)l,
      16, 0, 0);
}

// ------------------- x + Wp + Wc fp32 -> bf16, ONE dispatch -----------------
// Grid-stride, 8 elems (32B read / 16B write) per lane-iter.
__global__ __launch_bounds__(256) void cast_all(
    const float* __restrict__ x, const float* __restrict__ Wp,
    const float* __restrict__ Wc, unsigned short* __restrict__ xb,
    unsigned short* __restrict__ wpb, unsigned short* __restrict__ wcb) {
  const long nvec = 35651584 / 8;   // segments all divisible by 8
  for (long v = (long)blockIdx.x * 256 + threadIdx.x; v < nvec;
       v += (long)gridDim.x * 256) {
    const long i = v * 8;
    const float* s;
    unsigned short* d;
    long j;
    if (i < 33554432)      { s = x;  d = xb;  j = i; }
    else if (i < 34603008) { s = Wp; d = wpb; j = i - 33554432; }
    else                   { s = Wc; d = wcb; j = i - 34603008; }
    const float4 a = *(const float4*)(s + j);
    const float4 b = *(const float4*)(s + j + 4);
    ushort4 o0, o1;
    o0.x = f2bf(a.x); o0.y = f2bf(a.y); o0.z = f2bf(a.z); o0.w = f2bf(a.w);
    o1.x = f2bf(b.x); o1.y = f2bf(b.y); o1.z = f2bf(b.z); o1.w = f2bf(b.w);
    *(ushort4*)(d + j) = o0;
    *(ushort4*)(d + j + 4) = o1;
  }
}

constexpr int BM = 256, BN = 256, BK = 64;
constexpr int Kdim = 1024, Ndim = 1024;
constexpr int KT = Kdim / BK;   // 16

// C[m,n] = sum_k A[m,k]*B[n,k]  (B row-major [N,K]).
// EPI==1: store bf16 cos(acc + phi[n]); EPI==0: store fp32 acc.
// 512 threads = 8 waves (2M x 4N); per-wave C tile 128x64.
// LDS: [buf][kh][256 rows][32 kcols] bf16 per matrix (64 KB each).
// T2 swizzle: LDS chunk q of row r holds global 16B-chunk q ^ ((r>>1)&3);
// applied on the GLOBAL source (dest linear, guideline 21), inverted on read.
template <int EPI>
__global__ __launch_bounds__(512, 2) void gemm256(
    const unsigned short* __restrict__ A,   // [M,1024] bf16
    const unsigned short* __restrict__ B,   // [1024,1024] bf16
    const float* __restrict__ phi,
    void* __restrict__ Cout) {
  __shared__ unsigned short As[2][2][256][32];   // 64 KB
  __shared__ unsigned short Bs[2][2][256][32];   // 64 KB

  const int tid    = threadIdx.x;
  const int lane   = tid & 63;
  const int wv     = tid >> 6;        // 0..7
  const int wr     = wv >> 2;         // 0..1  (M wave)
  const int wc     = wv & 3;          // 0..3  (N wave)
  const int lane15 = lane & 15;
  const int quad   = lane >> 4;
  const int swz8   = (quad ^ ((lane15 >> 1) & 3)) * 8;  // ds_read chunk unswizzle

  // Bijective XCD swizzle: 512 wgs = 8 XCDs x 64; 4 n-siblings contiguous so
  // each XCD holds complete A m-panels in its L2.
  const int wg   = ((blockIdx.x & 7) << 6) | (blockIdx.x >> 3);
  const long row0 = (long)(wg >> 2) * BM;
  const int  col0 = (wg & 3) * BN;

  // staging: lane l covers row = wv*32 + l/4 (+16 for 2nd issue), LDS chunk
  // l&3; global source chunk pre-swizzled so LDS dest stays linear.
  const int csrc8 = ((lane & 3) ^ ((lane >> 3) & 3)) * 8;
  const int rA    = wv * 32 + (lane >> 2);

  // Stage one (matrix, kh)-half: 32 rows x 32 kcols, 2 loads/wave, 16KB total.
#define SA(KT2, NB, KH)                                                        \
  {                                                                            \
    const unsigned short* g_ =                                                 \
        A + (row0 + rA) * Kdim + (KT2) * BK + (KH) * 32 + csrc8;               \
    async_load16(g_, &As[NB][KH][wv * 32][0]);                                 \
    async_load16(g_ + 16 * Kdim, &As[NB][KH][wv * 32 + 16][0]);                \
  }
#define SB(KT2, NB, KH)                                                        \
  {                                                                            \
    const unsigned short* g_ =                                                 \
        B + (long)(col0 + rA) * Kdim + (KT2) * BK + (KH) * 32 + csrc8;         \
    async_load16(g_, &Bs[NB][KH][wv * 32][0]);                                 \
    async_load16(g_ + 16 * Kdim, &Bs[NB][KH][wv * 32 + 16][0]);                \
  }

  f32x4 acc[8][4];
#pragma unroll
  for (int i = 0; i < 8; ++i)
#pragma unroll
    for (int n = 0; n < 4; ++n) {
      f32x4 z = {0.f, 0.f, 0.f, 0.f};
      acc[i][n] = z;
    }

  // Prologue: kh0(0) [4 loads], then the steady-state "previous tile" pattern
  // A1(0),B1(0),A0(1),B0(1) [8 loads]. vmcnt(8) = kh0(0) landed, 8 in flight.
  SA(0, 0, 0); SB(0, 0, 0);
  SA(0, 0, 1);
  SB(0, 0, 1);
  SA(1, 1, 0);
  SB(1, 1, 0);
  asm volatile("s_waitcnt vmcnt(8)" ::: "memory");
  __builtin_amdgcn_s_barrier();

#pragma unroll 2
  for (int kt = 0; kt < KT; ++kt) {
    const int cur = kt & 1;
    const int nxt = cur ^ 1;
    short8 af[4], bfr[4];

    // ---- P0: (mh=0, kh=0); stage A-kh1(kt+1) -> buf nxt ----
#pragma unroll
    for (int i = 0; i < 4; ++i)
      af[i] = *(const short8*)(&As[cur][0][wr * 128 + i * 16 + lane15][swz8]);
#pragma unroll
    for (int i = 0; i < 4; ++i)
      bfr[i] = *(const short8*)(&Bs[cur][0][wc * 64 + i * 16 + lane15][swz8]);
    if (kt + 1 < KT) SA(kt + 1, nxt, 1)
    __builtin_amdgcn_s_barrier();
    asm volatile("s_waitcnt lgkmcnt(0)" ::: "memory");
    __builtin_amdgcn_sched_barrier(0);
    __builtin_amdgcn_s_setprio(1);
#pragma unroll
    for (int i = 0; i < 4; ++i)
#pragma unroll
      for (int n = 0; n < 4; ++n)
        acc[i][n] = __builtin_amdgcn_mfma_f32_16x16x32_bf16(
            af[i], bfr[n], acc[i][n], 0, 0, 0);
    __builtin_amdgcn_s_setprio(0);
    __builtin_amdgcn_sched_barrier(0);
    __builtin_amdgcn_s_barrier();

    // ---- P1: (mh=1, kh=0), bfr reused; stage B-kh1(kt+1) -> buf nxt ----
#pragma unroll
    for (int i = 0; i < 4; ++i)
      af[i] =
          *(const short8*)(&As[cur][0][wr * 128 + (4 + i) * 16 + lane15][swz8]);
    if (kt + 1 < KT) SB(kt + 1, nxt, 1)
    __builtin_amdgcn_s_barrier();
    asm volatile("s_waitcnt lgkmcnt(0)" ::: "memory");
    __builtin_amdgcn_sched_barrier(0);
    __builtin_amdgcn_s_setprio(1);
#pragma unroll
    for (int i = 0; i < 4; ++i)
#pragma unroll
      for (int n = 0; n < 4; ++n)
        acc[4 + i][n] = __builtin_amdgcn_mfma_f32_16x16x32_bf16(
            af[i], bfr[n], acc[4 + i][n], 0, 0, 0);
    __builtin_amdgcn_s_setprio(0);
    __builtin_amdgcn_sched_barrier(0);
    // kh1(kt) must be resident (issued at (kt-1)P0/P1, 4-5 phases ago).
    if (kt < KT - 1) {
      asm volatile("s_waitcnt vmcnt(8)" ::: "memory");
    } else {
      asm volatile("s_waitcnt vmcnt(0)" ::: "memory");
    }
    __builtin_amdgcn_s_barrier();

    // ---- P2: (mh=0, kh=1); kh0(cur) is dead -> stage A-kh0(kt+2) there ----
#pragma unroll
    for (int i = 0; i < 4; ++i)
      af[i] = *(const short8*)(&As[cur][1][wr * 128 + i * 16 + lane15][swz8]);
#pragma unroll
    for (int i = 0; i < 4; ++i)
      bfr[i] = *(const short8*)(&Bs[cur][1][wc * 64 + i * 16 + lane15][swz8]);
    if (kt + 2 < KT) SA(kt + 2, cur, 0)
    __builtin_amdgcn_s_barrier();
    asm volatile("s_waitcnt lgkmcnt(0)" ::: "memory");
    __builtin_amdgcn_sched_barrier(0);
    __builtin_amdgcn_s_setprio(1);
#pragma unroll
    for (int i = 0; i < 4; ++i)
#pragma unroll
      for (int n = 0; n < 4; ++n)
        acc[i][n] = __builtin_amdgcn_mfma_f32_16x16x32_bf16(
            af[i], bfr[n], acc[i][n], 0, 0, 0);
    __builtin_amdgcn_s_setprio(0);
    __builtin_amdgcn_sched_barrier(0);
    __builtin_amdgcn_s_barrier();

    // ---- P3: (mh=1, kh=1), bfr reused; stage B-kh0(kt+2) ----
#pragma unroll
    for (int i = 0; i < 4; ++i)
      af[i] =
          *(const short8*)(&As[cur][1][wr * 128 + (4 + i) * 16 + lane15][swz8]);
    if (kt + 2 < KT) SB(kt + 2, cur, 0)
    __builtin_amdgcn_s_barrier();
    asm volatile("s_waitcnt lgkmcnt(0)" ::: "memory");
    __builtin_amdgcn_sched_barrier(0);
    __builtin_amdgcn_s_setprio(1);
#pragma unroll
    for (int i = 0; i < 4; ++i)
#pragma unroll
      for (int n = 0; n < 4; ++n)
        acc[4 + i][n] = __builtin_amdgcn_mfma_f32_16x16x32_bf16(
            af[i], bfr[n], acc[4 + i][n], 0, 0, 0);
    __builtin_amdgcn_s_setprio(0);
    __builtin_amdgcn_sched_barrier(0);
    // kh0(kt+1) must be resident (issued at (kt-1)P2/P3, 4-5 phases ago).
    if (kt < KT - 2) {
      asm volatile("s_waitcnt vmcnt(8)" ::: "memory");
    } else if (kt == KT - 2) {
      asm volatile("s_waitcnt vmcnt(4)" ::: "memory");
    }
    __builtin_amdgcn_s_barrier();
  }
#undef SA
#undef SB

  // C/D layout (m89-verified): col = lane&15, row = quad*4 + reg.
  if (EPI == 1) {
    unsigned short* Q = (unsigned short*)Cout;
    float ph[4];
#pragma unroll
    for (int n = 0; n < 4; ++n)
      ph[n] = phi[col0 + wc * 64 + n * 16 + lane15];
#pragma unroll
    for (int mi = 0; mi < 8; ++mi) {
      const long rbase = row0 + wr * 128 + mi * 16 + quad * 4;
#pragma unroll
      for (int n = 0; n < 4; ++n) {
        const int c = col0 + wc * 64 + n * 16 + lane15;
#pragma unroll
        for (int r = 0; r < 4; ++r) {
          float v = __cosf(acc[mi][n][r] + ph[n]);
          Q[(rbase + r) * Ndim + c] = f2bf(v);
        }
      }
    }
  } else {
    float* C = (float*)Cout;
#pragma unroll
    for (int mi = 0; mi < 8; ++mi) {
      const long rbase = row0 + wr * 128 + mi * 16 + quad * 4;
#pragma unroll
      for (int n = 0; n < 4; ++n) {
        const int c = col0 + wc * 64 + n * 16 + lane15;
#pragma unroll
        for (int r = 0; r < 4; ++r)
          C[(rbase + r) * Ndim + c] = acc[mi][n][r];
      }
    }
  }
}

// ------------------------------- launch -------------------------------------
extern "C" void kernel_launch(void* const* d_in, const int* in_sizes, int n_in,
                              void* d_out, int out_size, void* d_ws, size_t ws_size,
                              hipStream_t stream) {
  const float* x   = (const float*)d_in[0];
  const float* Wp  = (const float*)d_in[1];
  const float* Wc  = (const float*)d_in[2];
  const float* phi = (const float*)d_in[3];
  float* out = (float*)d_out;

  // ws: Abf @0 (64 MB), Qbf @64 MB (64 MB), Wpbf @128 MB (2 MB), Wcbf (2 MB)
  char* ws = (char*)d_ws;
  unsigned short* Abf  = (unsigned short*)(ws);
  unsigned short* Qbf  = (unsigned short*)(ws + (size_t)67108864);
  unsigned short* Wpbf = (unsigned short*)(ws + (size_t)134217728);
  unsigned short* Wcbf = (unsigned short*)(ws + (size_t)136314880);

  cast_all<<<4096, 256, 0, stream>>>(x, Wp, Wc, Abf, Wpbf, Wcbf);
  gemm256<1><<<512, 512, 0, stream>>>(Abf, Wpbf, phi, (void*)Qbf);
  gemm256<0><<<512, 512, 0, stream>>>(Qbf, Wcbf, nullptr, (void*)out);

  (void)in_sizes; (void)n_in; (void)out_size; (void)ws_size;
}

// Round 3
// 371.590 us; speedup vs baseline: 1.0674x; 1.0330x over previous
//
#include <hip/hip_runtime.h>
#include <cstdint>
#include <cstddef>

// ---------------------------------------------------------------------------
// out = cos(x @ Wp^T + phi) @ Wc^T
//   x: [32768,1024] fp32, Wp/Wc: [1024,1024] fp32, phi flat [1024] fp32.
// R6: amortize per-phase fixed cost. Cycle model: MFMA floor = 33us/GEMM
// (19.4 cyc/MFMA/SIMD), measured 90.5us -> ~1000 wasted cyc per phase at 64
// phases/block. Now 2 phases/K-tile (32 MFMA each), ONE barrier per phase,
// no manual pre-MFMA lgkm drain (compiler emits counted lgkmcnt and
// interleaves ds_reads under the MFMA burst). Counted vmcnt(8) staging kept
// (1.5-tile depth, 4 loads/phase/wave). Accumulation order unchanged.
// ---------------------------------------------------------------------------

typedef __attribute__((ext_vector_type(8))) short short8;
typedef __attribute__((ext_vector_type(4))) float f32x4;

__device__ __forceinline__ unsigned short f2bf(float f) {
  unsigned u = __float_as_uint(f);
  u += 0x7FFFu + ((u >> 16) & 1u);   // RNE
  return (unsigned short)(u >> 16);
}

__device__ __forceinline__ void async_load16(const void* g, const void* l) {
  __builtin_amdgcn_global_load_lds(
      (const __attribute__((address_space(1))) void*)g,
      (__attribute__((address_space(3))) void*)l,
      16, 0, 0);
}

// ------------------- x + Wp + Wc fp32 -> bf16, ONE dispatch -----------------
// Grid-stride, 8 elems (32B read / one dwordx4 store) per lane-iter.
__global__ __launch_bounds__(256) void cast_all(
    const float* __restrict__ x, const float* __restrict__ Wp,
    const float* __restrict__ Wc, unsigned short* __restrict__ xb,
    unsigned short* __restrict__ wpb, unsigned short* __restrict__ wcb) {
  const long nvec = 35651584 / 8;
  for (long v = (long)blockIdx.x * 256 + threadIdx.x; v < nvec;
       v += (long)gridDim.x * 256) {
    const long i = v * 8;
    const float* s;
    unsigned short* d;
    long j;
    if (i < 33554432)      { s = x;  d = xb;  j = i; }
    else if (i < 34603008) { s = Wp; d = wpb; j = i - 33554432; }
    else                   { s = Wc; d = wcb; j = i - 34603008; }
    const float4 a = *(const float4*)(s + j);
    const float4 b = *(const float4*)(s + j + 4);
    uint4 o;
    o.x = (unsigned)f2bf(a.x) | ((unsigned)f2bf(a.y) << 16);
    o.y = (unsigned)f2bf(a.z) | ((unsigned)f2bf(a.w) << 16);
    o.z = (unsigned)f2bf(b.x) | ((unsigned)f2bf(b.y) << 16);
    o.w = (unsigned)f2bf(b.z) | ((unsigned)f2bf(b.w) << 16);
    *(uint4*)(d + j) = o;
  }
}

constexpr int BM = 256, BN = 256, BK = 64;
constexpr int Kdim = 1024, Ndim = 1024;
constexpr int KT = Kdim / BK;   // 16

// C[m,n] = sum_k A[m,k]*B[n,k]  (B row-major [N,K]).
// EPI==1: store bf16 cos(acc + phi[n]); EPI==0: store fp32 acc.
// 512 threads = 8 waves (2M x 4N); per-wave C tile 128x64.
// LDS: [buf][kh][256 rows][32 kcols] bf16 per matrix (64 KB each).
// T2 swizzle: LDS chunk q of row r holds global 16B-chunk q ^ ((r>>1)&3);
// applied on the GLOBAL source (dest linear, guideline 21), inverted on read.
template <int EPI>
__global__ __launch_bounds__(512, 2) void gemm256(
    const unsigned short* __restrict__ A,   // [M,1024] bf16
    const unsigned short* __restrict__ B,   // [1024,1024] bf16
    const float* __restrict__ phi,
    void* __restrict__ Cout) {
  __shared__ unsigned short As[2][2][256][32];   // 64 KB
  __shared__ unsigned short Bs[2][2][256][32];   // 64 KB

  const int tid    = threadIdx.x;
  const int lane   = tid & 63;
  const int wv     = tid >> 6;        // 0..7
  const int wr     = wv >> 2;         // 0..1  (M wave)
  const int wc     = wv & 3;          // 0..3  (N wave)
  const int lane15 = lane & 15;
  const int quad   = lane >> 4;
  const int swz8   = (quad ^ ((lane15 >> 1) & 3)) * 8;  // ds_read chunk unswizzle

  // Bijective XCD swizzle: 512 wgs = 8 XCDs x 64; 4 n-siblings contiguous so
  // each XCD holds complete A m-panels in its L2.
  const int wg   = ((blockIdx.x & 7) << 6) | (blockIdx.x >> 3);
  const long row0 = (long)(wg >> 2) * BM;
  const int  col0 = (wg & 3) * BN;

  // staging: lane l covers row = wv*32 + l/4 (+16 for 2nd issue), LDS chunk
  // l&3; global source chunk pre-swizzled so LDS dest stays linear.
  const int csrc8 = ((lane & 3) ^ ((lane >> 3) & 3)) * 8;
  const int rA    = wv * 32 + (lane >> 2);

  // Stage one (matrix, kh)-half: 256 rows x 32 kcols, 2 loads/wave each.
#define SA(KT2, NB, KH)                                                        \
  {                                                                            \
    const unsigned short* g_ =                                                 \
        A + (row0 + rA) * Kdim + (KT2) * BK + (KH) * 32 + csrc8;               \
    async_load16(g_, &As[NB][KH][wv * 32][0]);                                 \
    async_load16(g_ + 16 * Kdim, &As[NB][KH][wv * 32 + 16][0]);                \
  }
#define SB(KT2, NB, KH)                                                        \
  {                                                                            \
    const unsigned short* g_ =                                                 \
        B + (long)(col0 + rA) * Kdim + (KT2) * BK + (KH) * 32 + csrc8;         \
    async_load16(g_, &Bs[NB][KH][wv * 32][0]);                                 \
    async_load16(g_ + 16 * Kdim, &Bs[NB][KH][wv * 32 + 16][0]);                \
  }

  f32x4 acc[8][4];
#pragma unroll
  for (int i = 0; i < 8; ++i)
#pragma unroll
    for (int n = 0; n < 4; ++n) {
      f32x4 z = {0.f, 0.f, 0.f, 0.f};
      acc[i][n] = z;
    }

  // Prologue: kh0(0), kh1(0), kh0(1) staged (12 loads/wave).
  // vmcnt(8): kh0(0) resident, 8 in flight -- exactly steady state.
  SA(0, 0, 0); SB(0, 0, 0);
  SA(0, 0, 1); SB(0, 0, 1);
  SA(1, 1, 0); SB(1, 1, 0);
  asm volatile("s_waitcnt vmcnt(8)" ::: "memory");
  __builtin_amdgcn_s_barrier();

#pragma unroll 2
  for (int kt = 0; kt < KT; ++kt) {
    const int cur = kt & 1;
    const int nxt = cur ^ 1;
    short8 af[8], bfr[4];

    // ================ Phase A: kh0 of tile kt ================
    // reads of [cur][0]; stage kh1(kt+1) -> [nxt][1] (free since B(kt-1)).
#pragma unroll
    for (int i = 0; i < 8; ++i)
      af[i] = *(const short8*)(&As[cur][0][wr * 128 + i * 16 + lane15][swz8]);
#pragma unroll
    for (int n = 0; n < 4; ++n)
      bfr[n] = *(const short8*)(&Bs[cur][0][wc * 64 + n * 16 + lane15][swz8]);
    if (kt + 1 < KT) { SA(kt + 1, nxt, 1) SB(kt + 1, nxt, 1) }
    __builtin_amdgcn_s_setprio(1);
#pragma unroll
    for (int i = 0; i < 8; ++i)
#pragma unroll
      for (int n = 0; n < 4; ++n)
        acc[i][n] = __builtin_amdgcn_mfma_f32_16x16x32_bf16(
            af[i], bfr[n], acc[i][n], 0, 0, 0);
    __builtin_amdgcn_s_setprio(0);
    // Drain own LDS reads of [cur][0] (consumed; no stall expected), then
    // ensure kh1(kt) resident: after it, kh0(kt+1)@B(kt-1) [4] and
    // kh1(kt+1)@A(kt) [4] were issued -> vmcnt(8).
    asm volatile("s_waitcnt lgkmcnt(0)" ::: "memory");
    __builtin_amdgcn_sched_barrier(0);
    if (kt < KT - 1) {
      asm volatile("s_waitcnt vmcnt(8)" ::: "memory");
    } else {
      asm volatile("s_waitcnt vmcnt(0)" ::: "memory");
    }
    __builtin_amdgcn_s_barrier();

    // ================ Phase B: kh1 of tile kt ================
    // reads of [cur][1]; stage kh0(kt+2) -> [cur][0] (reads drained above).
#pragma unroll
    for (int i = 0; i < 8; ++i)
      af[i] = *(const short8*)(&As[cur][1][wr * 128 + i * 16 + lane15][swz8]);
#pragma unroll
    for (int n = 0; n < 4; ++n)
      bfr[n] = *(const short8*)(&Bs[cur][1][wc * 64 + n * 16 + lane15][swz8]);
    if (kt + 2 < KT) { SA(kt + 2, cur, 0) SB(kt + 2, cur, 0) }
    __builtin_amdgcn_s_setprio(1);
#pragma unroll
    for (int i = 0; i < 8; ++i)
#pragma unroll
      for (int n = 0; n < 4; ++n)
        acc[i][n] = __builtin_amdgcn_mfma_f32_16x16x32_bf16(
            af[i], bfr[n], acc[i][n], 0, 0, 0);
    __builtin_amdgcn_s_setprio(0);
    // Ensure kh0(kt+1) resident: after it, kh1(kt+1)@A(kt) [4] and
    // kh0(kt+2)@B(kt) [4] -> vmcnt(8); tail: vmcnt(4) at kt==KT-2.
    asm volatile("s_waitcnt lgkmcnt(0)" ::: "memory");
    __builtin_amdgcn_sched_barrier(0);
    if (kt < KT - 2) {
      asm volatile("s_waitcnt vmcnt(8)" ::: "memory");
    } else if (kt == KT - 2) {
      asm volatile("s_waitcnt vmcnt(4)" ::: "memory");
    }
    __builtin_amdgcn_s_barrier();
  }
#undef SA
#undef SB

  // C/D layout (m89-verified): col = lane&15, row = quad*4 + reg.
  if (EPI == 1) {
    unsigned short* Q = (unsigned short*)Cout;
    float ph[4];
#pragma unroll
    for (int n = 0; n < 4; ++n)
      ph[n] = phi[col0 + wc * 64 + n * 16 + lane15];
#pragma unroll
    for (int mi = 0; mi < 8; ++mi) {
      const long rbase = row0 + wr * 128 + mi * 16 + quad * 4;
#pragma unroll
      for (int n = 0; n < 4; ++n) {
        const int c = col0 + wc * 64 + n * 16 + lane15;
#pragma unroll
        for (int r = 0; r < 4; ++r) {
          float v = __cosf(acc[mi][n][r] + ph[n]);
          Q[(rbase + r) * Ndim + c] = f2bf(v);
        }
      }
    }
  } else {
    float* C = (float*)Cout;
#pragma unroll
    for (int mi = 0; mi < 8; ++mi) {
      const long rbase = row0 + wr * 128 + mi * 16 + quad * 4;
#pragma unroll
      for (int n = 0; n < 4; ++n) {
        const int c = col0 + wc * 64 + n * 16 + lane15;
#pragma unroll
        for (int r = 0; r < 4; ++r)
          C[(rbase + r) * Ndim + c] = acc[mi][n][r];
      }
    }
  }
}

// ------------------------------- launch -------------------------------------
extern "C" void kernel_launch(void* const* d_in, const int* in_sizes, int n_in,
                              void* d_out, int out_size, void* d_ws, size_t ws_size,
                              hipStream_t stream) {
  const float* x   = (const float*)d_in[0];
  const float* Wp  = (const float*)d_in[1];
  const float* Wc  = (const float*)d_in[2];
  const float* phi = (const float*)d_in[3];
  float* out = (float*)d_out;

  // ws: Abf @0 (64 MB), Qbf @64 MB (64 MB), Wpbf @128 MB (2 MB), Wcbf (2 MB)
  char* ws = (char*)d_ws;
  unsigned short* Abf  = (unsigned short*)(ws);
  unsigned short* Qbf  = (unsigned short*)(ws + (size_t)67108864);
  unsigned short* Wpbf = (unsigned short*)(ws + (size_t)134217728);
  unsigned short* Wcbf = (unsigned short*)(ws + (size_t)136314880);

  cast_all<<<4096, 256, 0, stream>>>(x, Wp, Wc, Abf, Wpbf, Wcbf);
  gemm256<1><<<512, 512, 0, stream>>>(Abf, Wpbf, phi, (void*)Qbf);
  gemm256<0><<<512, 512, 0, stream>>>(Qbf, Wcbf, nullptr, (void*)out);

  (void)in_sizes; (void)n_in; (void)out_size; (void)ws_size;
}